// Round 2
// baseline (705.509 us; speedup 1.0000x reference)
//
#include <hip/hip_runtime.h>

// ---------------------------------------------------------------------------
// 3-layer GCN (PyG GCNConv semantics, add_self_loops=False) on MI355X.
//   deg[dst]++ -> dinv=rsqrt(deg) -> rowptr=exscan(deg)
//   fill CSR as int2{src, w_bits}, w = dinv[src]*dinv[dst]
//   L1: h=x@W1 ; g=gather(h)+b1 -> BN -> ReLU
//   L2: h=g@W2 ; g=gather(h)+b2 -> BN -> ReLU
//   L3: h=g@W3 ; out=gather(h)+b3
// Gather: 1 wave/node, 4 groups of 16 lanes, each group takes every 4th edge,
// float4 per lane (16 lanes x 16B = full 64-float row), unroll x2 => up to 8
// H-row loads in flight per wave (round-1 profile showed latency-bound: HBM
// 17.8%, VALU 17%).
// ---------------------------------------------------------------------------

constexpr int SCAN_T = 256;
constexpr int SCAN_E = 8;
constexpr int SCAN_B = SCAN_T * SCAN_E; // 2048 elems per scan block

__global__ __launch_bounds__(256) void k_count_deg(const int* __restrict__ dst,
                                                   int* __restrict__ deg, int E) {
  int e = blockIdx.x * 256 + threadIdx.x;
  if (e < E) atomicAdd(&deg[dst[e]], 1);
}

__global__ __launch_bounds__(256) void k_dinv(const int* __restrict__ deg,
                                              float* __restrict__ dinv, int N) {
  int i = blockIdx.x * 256 + threadIdx.x;
  if (i < N) {
    int d = deg[i];
    dinv[i] = (d > 0) ? rsqrtf((float)d) : 0.f;
  }
}

__global__ __launch_bounds__(SCAN_T) void k_scan1(const int* __restrict__ deg,
                                                  int* __restrict__ pre,
                                                  int* __restrict__ bsum, int N) {
  __shared__ int ls[SCAN_T];
  int t = threadIdx.x;
  int base = blockIdx.x * SCAN_B + t * SCAN_E;
  int v[SCAN_E];
  int s = 0;
#pragma unroll
  for (int j = 0; j < SCAN_E; ++j) {
    int idx = base + j;
    v[j] = (idx < N) ? deg[idx] : 0;
    s += v[j];
  }
  ls[t] = s;
  __syncthreads();
  for (int off = 1; off < SCAN_T; off <<= 1) {
    int x = 0;
    if (t >= off) x = ls[t - off];
    __syncthreads();
    ls[t] += x;
    __syncthreads();
  }
  if (t == SCAN_T - 1) bsum[blockIdx.x] = ls[t];
  int run = (t > 0) ? ls[t - 1] : 0;
#pragma unroll
  for (int j = 0; j < SCAN_E; ++j) {
    int idx = base + j;
    if (idx < N) pre[idx] = run;
    run += v[j];
  }
}

__global__ __launch_bounds__(SCAN_T) void k_scan2(int* __restrict__ bsum, int nb) {
  __shared__ int ls[SCAN_T];
  int t = threadIdx.x;
  ls[t] = (t < nb) ? bsum[t] : 0;
  __syncthreads();
  for (int off = 1; off < SCAN_T; off <<= 1) {
    int x = 0;
    if (t >= off) x = ls[t - off];
    __syncthreads();
    ls[t] += x;
    __syncthreads();
  }
  if (t < nb) bsum[t] = (t > 0) ? ls[t - 1] : 0;
}

__global__ __launch_bounds__(256) void k_scan3(int* __restrict__ rowptr,
                                               const int* __restrict__ bsum,
                                               int N, int E) {
  int i = blockIdx.x * 256 + threadIdx.x;
  if (i < N) rowptr[i] += bsum[i / SCAN_B];
  if (i == 0) rowptr[N] = E;
}

__global__ __launch_bounds__(256) void k_fill(const int* __restrict__ src,
                                              const int* __restrict__ dst,
                                              const float* __restrict__ dinv,
                                              const int* __restrict__ rowptr,
                                              int* __restrict__ fillc,
                                              int2* __restrict__ csr, int E) {
  int e = blockIdx.x * 256 + threadIdx.x;
  if (e >= E) return;
  int d = dst[e], s = src[e];
  int slot = atomicAdd(&fillc[d], 1);
  int p = rowptr[d] + slot;
  csr[p] = make_int2(s, __float_as_int(dinv[s] * dinv[d]));
}

// H[N,F] = X[N,K] @ W[K,F]. One block = 16 rows/iter (4 rows per wave,
// 4 accumulators per lane) so each LDS read of W[k][lane] feeds 4 FMAs.
template <int K, int F>
__global__ __launch_bounds__(256) void k_gemm(const float* __restrict__ X,
                                              const float* __restrict__ W,
                                              float* __restrict__ H, int N) {
  __shared__ float Wl[K * F];
  __shared__ float Xl[16][K];
  for (int i = threadIdx.x; i < K * F / 4; i += 256)
    *reinterpret_cast<float4*>(&Wl[i * 4]) =
        *reinterpret_cast<const float4*>(&W[i * 4]);
  int wv = threadIdx.x >> 6, lane = threadIdx.x & 63;
  for (int row0 = blockIdx.x * 16; row0 < N; row0 += gridDim.x * 16) {
    __syncthreads();  // Wl visible (1st iter) / previous Xl reads done
    constexpr int XE = 16 * K / 4;
    for (int i = threadIdx.x; i < XE; i += 256) {
      int r = (i * 4) / K, c = (i * 4) % K;
      int row = row0 + r;
      float4 v = make_float4(0.f, 0.f, 0.f, 0.f);
      if (row < N) v = *reinterpret_cast<const float4*>(&X[(size_t)row * K + c]);
      *reinterpret_cast<float4*>(&Xl[r][c]) = v;
    }
    __syncthreads();
    if (lane < F) {
      float acc0 = 0.f, acc1 = 0.f, acc2 = 0.f, acc3 = 0.f;
#pragma unroll
      for (int k = 0; k < K; ++k) {
        float w = Wl[k * F + lane];
        acc0 = fmaf(Xl[wv * 4 + 0][k], w, acc0);
        acc1 = fmaf(Xl[wv * 4 + 1][k], w, acc1);
        acc2 = fmaf(Xl[wv * 4 + 2][k], w, acc2);
        acc3 = fmaf(Xl[wv * 4 + 3][k], w, acc3);
      }
      int row = row0 + wv * 4;
      if (row + 0 < N) H[(size_t)(row + 0) * F + lane] = acc0;
      if (row + 1 < N) H[(size_t)(row + 1) * F + lane] = acc1;
      if (row + 2 < N) H[(size_t)(row + 2) * F + lane] = acc2;
      if (row + 3 < N) H[(size_t)(row + 3) * F + lane] = acc3;
    }
  }
}

// G[i,:] = BN/ReLU( sum_p w_p * H[src_p,:] + bias ).  1 wave/node; 4 groups of
// 16 lanes take edges p0+g, p0+g+4, ... ; lane gl covers features gl*4..gl*4+3
// as float4; unroll x2; cross-group shuffle reduce at the end.
template <int F, bool BNR>
__global__ __launch_bounds__(256) void k_agg(const float* __restrict__ H,
                                             float* __restrict__ G,
                                             const int* __restrict__ rowptr,
                                             const int2* __restrict__ csr,
                                             const float* __restrict__ bias,
                                             const float* __restrict__ gam,
                                             const float* __restrict__ bet,
                                             const float* __restrict__ mu,
                                             const float* __restrict__ var, int N) {
  constexpr int LPG = F / 4;  // active lanes per 16-lane group (16 for 64, 10 for 40)
  int node = (blockIdx.x * 256 + threadIdx.x) >> 6;
  int lane = threadIdx.x & 63;
  if (node >= N) return;
  int g = lane >> 4, gl = lane & 15;
  bool active = gl < LPG;
  int p0 = rowptr[node], p1 = rowptr[node + 1];
  float4 a0 = make_float4(0.f, 0.f, 0.f, 0.f);
  float4 a1 = make_float4(0.f, 0.f, 0.f, 0.f);
  int p = p0 + g;
  for (; p + 4 < p1; p += 8) {
    int2 e0 = csr[p];
    int2 e1 = csr[p + 4];
    if (active) {
      float4 h0 = *reinterpret_cast<const float4*>(&H[(size_t)e0.x * F + gl * 4]);
      float4 h1 = *reinterpret_cast<const float4*>(&H[(size_t)e1.x * F + gl * 4]);
      float w0 = __int_as_float(e0.y), w1 = __int_as_float(e1.y);
      a0.x = fmaf(w0, h0.x, a0.x); a0.y = fmaf(w0, h0.y, a0.y);
      a0.z = fmaf(w0, h0.z, a0.z); a0.w = fmaf(w0, h0.w, a0.w);
      a1.x = fmaf(w1, h1.x, a1.x); a1.y = fmaf(w1, h1.y, a1.y);
      a1.z = fmaf(w1, h1.z, a1.z); a1.w = fmaf(w1, h1.w, a1.w);
    }
  }
  if (p < p1) {
    int2 e0 = csr[p];
    if (active) {
      float4 h0 = *reinterpret_cast<const float4*>(&H[(size_t)e0.x * F + gl * 4]);
      float w0 = __int_as_float(e0.y);
      a0.x = fmaf(w0, h0.x, a0.x); a0.y = fmaf(w0, h0.y, a0.y);
      a0.z = fmaf(w0, h0.z, a0.z); a0.w = fmaf(w0, h0.w, a0.w);
    }
  }
  a0.x += a1.x; a0.y += a1.y; a0.z += a1.z; a0.w += a1.w;
#pragma unroll
  for (int off = 16; off <= 32; off <<= 1) {
    a0.x += __shfl_xor(a0.x, off);
    a0.y += __shfl_xor(a0.y, off);
    a0.z += __shfl_xor(a0.z, off);
    a0.w += __shfl_xor(a0.w, off);
  }
  if (g == 0 && active) {
    int f = gl * 4;
    float4 y = a0;
    y.x += bias[f + 0]; y.y += bias[f + 1]; y.z += bias[f + 2]; y.w += bias[f + 3];
    if (BNR) {
      y.x = fmaxf((y.x - mu[f + 0]) * rsqrtf(var[f + 0] + 1e-5f) * gam[f + 0] + bet[f + 0], 0.f);
      y.y = fmaxf((y.y - mu[f + 1]) * rsqrtf(var[f + 1] + 1e-5f) * gam[f + 1] + bet[f + 1], 0.f);
      y.z = fmaxf((y.z - mu[f + 2]) * rsqrtf(var[f + 2] + 1e-5f) * gam[f + 2] + bet[f + 2], 0.f);
      y.w = fmaxf((y.w - mu[f + 3]) * rsqrtf(var[f + 3] + 1e-5f) * gam[f + 3] + bet[f + 3], 0.f);
    }
    *reinterpret_cast<float4*>(&G[(size_t)node * F + f]) = y;
  }
}

extern "C" void kernel_launch(void* const* d_in, const int* in_sizes, int n_in,
                              void* d_out, int out_size, void* d_ws, size_t ws_size,
                              hipStream_t stream) {
  const float* x  = (const float*)d_in[0];
  const int*   ei = (const int*)d_in[1];
  const float* W1 = (const float*)d_in[2];
  const float* b1 = (const float*)d_in[3];
  const float* W2 = (const float*)d_in[4];
  const float* b2 = (const float*)d_in[5];
  const float* W3 = (const float*)d_in[6];
  const float* b3 = (const float*)d_in[7];
  const float* g1 = (const float*)d_in[8];
  const float* be1 = (const float*)d_in[9];
  const float* m1 = (const float*)d_in[10];
  const float* v1 = (const float*)d_in[11];
  const float* g2 = (const float*)d_in[12];
  const float* be2 = (const float*)d_in[13];
  const float* m2 = (const float*)d_in[14];
  const float* v2 = (const float*)d_in[15];

  const int N = in_sizes[0] / 128;  // 100000
  const int E = in_sizes[1] / 2;    // 1000000
  const int* src = ei;
  const int* dst = ei + E;

  char* w = (char*)d_ws;
  size_t off = 0;
  auto take = [&](size_t bytes) -> void* {
    void* p = w + off;
    off += (bytes + 511) & ~size_t(511);
    return p;
  };
  int*   deg     = (int*)take((size_t)N * 4);
  int*   fillc   = (int*)take((size_t)N * 4);
  size_t zeroB   = off;  // deg + fillc contiguous from 0
  int*   rowptr  = (int*)take(((size_t)N + 1) * 4);
  float* dinv    = (float*)take((size_t)N * 4);
  int*   bsum    = (int*)take((size_t)SCAN_T * 4);
  int2*  csr     = (int2*)take((size_t)E * 8);
  float* bufA    = (float*)take((size_t)N * 64 * 4);
  float* bufB    = (float*)take((size_t)N * 64 * 4);
  if (off > ws_size) return;

  const int nb = (N + SCAN_B - 1) / SCAN_B;  // 49

  hipMemsetAsync(d_ws, 0, zeroB, stream);
  k_count_deg<<<(E + 255) / 256, 256, 0, stream>>>(dst, deg, E);
  k_dinv<<<(N + 255) / 256, 256, 0, stream>>>(deg, dinv, N);
  k_scan1<<<nb, SCAN_T, 0, stream>>>(deg, rowptr, bsum, N);
  k_scan2<<<1, SCAN_T, 0, stream>>>(bsum, nb);
  k_scan3<<<(N + 255) / 256, 256, 0, stream>>>(rowptr, bsum, N, E);
  k_fill<<<(E + 255) / 256, 256, 0, stream>>>(src, dst, dinv, rowptr, fillc, csr, E);

  // layer 1
  k_gemm<128, 64><<<2048, 256, 0, stream>>>(x, W1, bufA, N);
  k_agg<64, true><<<(N + 3) / 4, 256, 0, stream>>>(bufA, bufB, rowptr, csr,
                                                   b1, g1, be1, m1, v1, N);
  // layer 2
  k_gemm<64, 64><<<2048, 256, 0, stream>>>(bufB, W2, bufA, N);
  k_agg<64, true><<<(N + 3) / 4, 256, 0, stream>>>(bufA, bufB, rowptr, csr,
                                                   b2, g2, be2, m2, v2, N);
  // output layer
  k_gemm<64, 40><<<2048, 256, 0, stream>>>(bufB, W3, bufA, N);
  k_agg<40, false><<<(N + 3) / 4, 256, 0, stream>>>(
      bufA, (float*)d_out, rowptr, csr, b3, nullptr, nullptr, nullptr, nullptr, N);
}

// Round 3
// 316.728 us; speedup vs baseline: 2.2275x; 2.2275x over previous
//
#include <hip/hip_runtime.h>

// ---------------------------------------------------------------------------
// 3-layer GCN (PyG GCNConv semantics, add_self_loops=False) on MI355X.
//   deg[dst]++ -> dinv=rsqrt(deg) -> rowptr=exscan(deg)
//   fill CSR as int2{src, w_bits}, w = dinv[src]*dinv[dst]
//   L1: h=x@W1 ; g=gather(h)+b1 -> BN -> ReLU
//   L2: h=g@W2 ; g=gather(h)+b2 -> BN -> ReLU
//   L3: h=g@W3 ; out=gather(h)+b3
// GEMM: register-tiled 4 rows x 4 cols per thread, W+X in LDS, partial
// unroll (round-2 full-unroll version spilled: VGPR=256, 775MB scratch
// writes, 395us).  Gather: 1 wave/node, 4x16-lane groups, float4 rows.
// ---------------------------------------------------------------------------

constexpr int SCAN_T = 256;
constexpr int SCAN_E = 8;
constexpr int SCAN_B = SCAN_T * SCAN_E; // 2048 elems per scan block

__global__ __launch_bounds__(256) void k_count_deg(const int* __restrict__ dst,
                                                   int* __restrict__ deg, int E) {
  int e = blockIdx.x * 256 + threadIdx.x;
  if (e < E) atomicAdd(&deg[dst[e]], 1);
}

__global__ __launch_bounds__(256) void k_dinv(const int* __restrict__ deg,
                                              float* __restrict__ dinv, int N) {
  int i = blockIdx.x * 256 + threadIdx.x;
  if (i < N) {
    int d = deg[i];
    dinv[i] = (d > 0) ? rsqrtf((float)d) : 0.f;
  }
}

__global__ __launch_bounds__(SCAN_T) void k_scan1(const int* __restrict__ deg,
                                                  int* __restrict__ pre,
                                                  int* __restrict__ bsum, int N) {
  __shared__ int ls[SCAN_T];
  int t = threadIdx.x;
  int base = blockIdx.x * SCAN_B + t * SCAN_E;
  int v[SCAN_E];
  int s = 0;
#pragma unroll
  for (int j = 0; j < SCAN_E; ++j) {
    int idx = base + j;
    v[j] = (idx < N) ? deg[idx] : 0;
    s += v[j];
  }
  ls[t] = s;
  __syncthreads();
  for (int off = 1; off < SCAN_T; off <<= 1) {
    int x = 0;
    if (t >= off) x = ls[t - off];
    __syncthreads();
    ls[t] += x;
    __syncthreads();
  }
  if (t == SCAN_T - 1) bsum[blockIdx.x] = ls[t];
  int run = (t > 0) ? ls[t - 1] : 0;
#pragma unroll
  for (int j = 0; j < SCAN_E; ++j) {
    int idx = base + j;
    if (idx < N) pre[idx] = run;
    run += v[j];
  }
}

__global__ __launch_bounds__(SCAN_T) void k_scan2(int* __restrict__ bsum, int nb) {
  __shared__ int ls[SCAN_T];
  int t = threadIdx.x;
  ls[t] = (t < nb) ? bsum[t] : 0;
  __syncthreads();
  for (int off = 1; off < SCAN_T; off <<= 1) {
    int x = 0;
    if (t >= off) x = ls[t - off];
    __syncthreads();
    ls[t] += x;
    __syncthreads();
  }
  if (t < nb) bsum[t] = (t > 0) ? ls[t - 1] : 0;
}

__global__ __launch_bounds__(256) void k_scan3(int* __restrict__ rowptr,
                                               const int* __restrict__ bsum,
                                               int N, int E) {
  int i = blockIdx.x * 256 + threadIdx.x;
  if (i < N) rowptr[i] += bsum[i / SCAN_B];
  if (i == 0) rowptr[N] = E;
}

__global__ __launch_bounds__(256) void k_fill(const int* __restrict__ src,
                                              const int* __restrict__ dst,
                                              const float* __restrict__ dinv,
                                              const int* __restrict__ rowptr,
                                              int* __restrict__ fillc,
                                              int2* __restrict__ csr, int E) {
  int e = blockIdx.x * 256 + threadIdx.x;
  if (e >= E) return;
  int d = dst[e], s = src[e];
  int slot = atomicAdd(&fillc[d], 1);
  int p = rowptr[d] + slot;
  csr[p] = make_int2(s, __float_as_int(dinv[s] * dinv[d]));
}

// H[N,F] = X[N,K] @ W[K,F].  Register-tiled: thread = 4 rows x 4 cols (16
// fp32 acc).  CG = F/4 col-groups, RG = 256/CG row-groups, ROWS = 4*RG rows
// per block.  X staged in LDS padded [+4 floats] so the per-k broadcast
// reads of 4 rows land on different banks; W staged [K][F], read as float4.
template <int K, int F>
__global__ __launch_bounds__(256) void k_gemm(const float* __restrict__ X,
                                              const float* __restrict__ W,
                                              float* __restrict__ H, int N) {
  constexpr int CG = F / 4;        // 16 (F=64) or 10 (F=40)
  constexpr int RG = 256 / CG;     // 16 or 25
  constexpr int ROWS = RG * 4;     // 64 or 100
  constexpr int XP = K + 4;        // padded X row stride (floats)
  __shared__ float Wl[K * F];
  __shared__ float Xl[ROWS * XP];

  const int t = threadIdx.x;
  const int row0 = blockIdx.x * ROWS;

  // stage W (float4 copy)
  for (int i = t; i < K * F / 4; i += 256)
    *reinterpret_cast<float4*>(&Wl[i * 4]) =
        *reinterpret_cast<const float4*>(&W[i * 4]);
  // stage X rows row0..row0+ROWS-1, zero-padded past N
  for (int i = t; i < ROWS * K / 4; i += 256) {
    int r = (i * 4) / K, c = (i * 4) % K;
    int row = row0 + r;
    float4 v = make_float4(0.f, 0.f, 0.f, 0.f);
    if (row < N) v = *reinterpret_cast<const float4*>(&X[(size_t)row * K + c]);
    *reinterpret_cast<float4*>(&Xl[r * XP + c]) = v;
  }
  __syncthreads();

  if (t < CG * RG) {
    const int cg = t % CG;   // col group (4 cols)
    const int rg = t / CG;   // row group (4 rows)
    float4 a0 = make_float4(0.f, 0.f, 0.f, 0.f);
    float4 a1 = make_float4(0.f, 0.f, 0.f, 0.f);
    float4 a2 = make_float4(0.f, 0.f, 0.f, 0.f);
    float4 a3 = make_float4(0.f, 0.f, 0.f, 0.f);
    const float* xr = &Xl[rg * 4 * XP];
#pragma unroll 4
    for (int k = 0; k < K; ++k) {
      float4 wv = *reinterpret_cast<const float4*>(&Wl[k * F + cg * 4]);
      float x0 = xr[0 * XP + k];
      float x1 = xr[1 * XP + k];
      float x2 = xr[2 * XP + k];
      float x3 = xr[3 * XP + k];
      a0.x = fmaf(x0, wv.x, a0.x); a0.y = fmaf(x0, wv.y, a0.y);
      a0.z = fmaf(x0, wv.z, a0.z); a0.w = fmaf(x0, wv.w, a0.w);
      a1.x = fmaf(x1, wv.x, a1.x); a1.y = fmaf(x1, wv.y, a1.y);
      a1.z = fmaf(x1, wv.z, a1.z); a1.w = fmaf(x1, wv.w, a1.w);
      a2.x = fmaf(x2, wv.x, a2.x); a2.y = fmaf(x2, wv.y, a2.y);
      a2.z = fmaf(x2, wv.z, a2.z); a2.w = fmaf(x2, wv.w, a2.w);
      a3.x = fmaf(x3, wv.x, a3.x); a3.y = fmaf(x3, wv.y, a3.y);
      a3.z = fmaf(x3, wv.z, a3.z); a3.w = fmaf(x3, wv.w, a3.w);
    }
    const int col = cg * 4;
    const int row = row0 + rg * 4;
    if (row + 0 < N) *reinterpret_cast<float4*>(&H[(size_t)(row + 0) * F + col]) = a0;
    if (row + 1 < N) *reinterpret_cast<float4*>(&H[(size_t)(row + 1) * F + col]) = a1;
    if (row + 2 < N) *reinterpret_cast<float4*>(&H[(size_t)(row + 2) * F + col]) = a2;
    if (row + 3 < N) *reinterpret_cast<float4*>(&H[(size_t)(row + 3) * F + col]) = a3;
  }
}

// G[i,:] = BN/ReLU( sum_p w_p * H[src_p,:] + bias ).  1 wave/node; 4 groups of
// 16 lanes take edges p0+g, p0+g+4, ... ; lane gl covers features gl*4..gl*4+3
// as float4; unroll x2; cross-group shuffle reduce at the end.
template <int F, bool BNR>
__global__ __launch_bounds__(256) void k_agg(const float* __restrict__ H,
                                             float* __restrict__ G,
                                             const int* __restrict__ rowptr,
                                             const int2* __restrict__ csr,
                                             const float* __restrict__ bias,
                                             const float* __restrict__ gam,
                                             const float* __restrict__ bet,
                                             const float* __restrict__ mu,
                                             const float* __restrict__ var, int N) {
  constexpr int LPG = F / 4;  // active lanes per 16-lane group
  int node = (blockIdx.x * 256 + threadIdx.x) >> 6;
  int lane = threadIdx.x & 63;
  if (node >= N) return;
  int g = lane >> 4, gl = lane & 15;
  bool active = gl < LPG;
  int p0 = rowptr[node], p1 = rowptr[node + 1];
  float4 a0 = make_float4(0.f, 0.f, 0.f, 0.f);
  float4 a1 = make_float4(0.f, 0.f, 0.f, 0.f);
  int p = p0 + g;
  for (; p + 4 < p1; p += 8) {
    int2 e0 = csr[p];
    int2 e1 = csr[p + 4];
    if (active) {
      float4 h0 = *reinterpret_cast<const float4*>(&H[(size_t)e0.x * F + gl * 4]);
      float4 h1 = *reinterpret_cast<const float4*>(&H[(size_t)e1.x * F + gl * 4]);
      float w0 = __int_as_float(e0.y), w1 = __int_as_float(e1.y);
      a0.x = fmaf(w0, h0.x, a0.x); a0.y = fmaf(w0, h0.y, a0.y);
      a0.z = fmaf(w0, h0.z, a0.z); a0.w = fmaf(w0, h0.w, a0.w);
      a1.x = fmaf(w1, h1.x, a1.x); a1.y = fmaf(w1, h1.y, a1.y);
      a1.z = fmaf(w1, h1.z, a1.z); a1.w = fmaf(w1, h1.w, a1.w);
    }
  }
  if (p < p1) {
    int2 e0 = csr[p];
    if (active) {
      float4 h0 = *reinterpret_cast<const float4*>(&H[(size_t)e0.x * F + gl * 4]);
      float w0 = __int_as_float(e0.y);
      a0.x = fmaf(w0, h0.x, a0.x); a0.y = fmaf(w0, h0.y, a0.y);
      a0.z = fmaf(w0, h0.z, a0.z); a0.w = fmaf(w0, h0.w, a0.w);
    }
  }
  a0.x += a1.x; a0.y += a1.y; a0.z += a1.z; a0.w += a1.w;
#pragma unroll
  for (int off = 16; off <= 32; off <<= 1) {
    a0.x += __shfl_xor(a0.x, off);
    a0.y += __shfl_xor(a0.y, off);
    a0.z += __shfl_xor(a0.z, off);
    a0.w += __shfl_xor(a0.w, off);
  }
  if (g == 0 && active) {
    int f = gl * 4;
    float4 y = a0;
    y.x += bias[f + 0]; y.y += bias[f + 1]; y.z += bias[f + 2]; y.w += bias[f + 3];
    if (BNR) {
      y.x = fmaxf((y.x - mu[f + 0]) * rsqrtf(var[f + 0] + 1e-5f) * gam[f + 0] + bet[f + 0], 0.f);
      y.y = fmaxf((y.y - mu[f + 1]) * rsqrtf(var[f + 1] + 1e-5f) * gam[f + 1] + bet[f + 1], 0.f);
      y.z = fmaxf((y.z - mu[f + 2]) * rsqrtf(var[f + 2] + 1e-5f) * gam[f + 2] + bet[f + 2], 0.f);
      y.w = fmaxf((y.w - mu[f + 3]) * rsqrtf(var[f + 3] + 1e-5f) * gam[f + 3] + bet[f + 3], 0.f);
    }
    *reinterpret_cast<float4*>(&G[(size_t)node * F + f]) = y;
  }
}

extern "C" void kernel_launch(void* const* d_in, const int* in_sizes, int n_in,
                              void* d_out, int out_size, void* d_ws, size_t ws_size,
                              hipStream_t stream) {
  const float* x  = (const float*)d_in[0];
  const int*   ei = (const int*)d_in[1];
  const float* W1 = (const float*)d_in[2];
  const float* b1 = (const float*)d_in[3];
  const float* W2 = (const float*)d_in[4];
  const float* b2 = (const float*)d_in[5];
  const float* W3 = (const float*)d_in[6];
  const float* b3 = (const float*)d_in[7];
  const float* g1 = (const float*)d_in[8];
  const float* be1 = (const float*)d_in[9];
  const float* m1 = (const float*)d_in[10];
  const float* v1 = (const float*)d_in[11];
  const float* g2 = (const float*)d_in[12];
  const float* be2 = (const float*)d_in[13];
  const float* m2 = (const float*)d_in[14];
  const float* v2 = (const float*)d_in[15];

  const int N = in_sizes[0] / 128;  // 100000
  const int E = in_sizes[1] / 2;    // 1000000
  const int* src = ei;
  const int* dst = ei + E;

  char* w = (char*)d_ws;
  size_t off = 0;
  auto take = [&](size_t bytes) -> void* {
    void* p = w + off;
    off += (bytes + 511) & ~size_t(511);
    return p;
  };
  int*   deg     = (int*)take((size_t)N * 4);
  int*   fillc   = (int*)take((size_t)N * 4);
  size_t zeroB   = off;  // deg + fillc contiguous from 0
  int*   rowptr  = (int*)take(((size_t)N + 1) * 4);
  float* dinv    = (float*)take((size_t)N * 4);
  int*   bsum    = (int*)take((size_t)SCAN_T * 4);
  int2*  csr     = (int2*)take((size_t)E * 8);
  float* bufA    = (float*)take((size_t)N * 64 * 4);
  float* bufB    = (float*)take((size_t)N * 64 * 4);
  if (off > ws_size) return;

  const int nb = (N + SCAN_B - 1) / SCAN_B;  // 49

  hipMemsetAsync(d_ws, 0, zeroB, stream);
  k_count_deg<<<(E + 255) / 256, 256, 0, stream>>>(dst, deg, E);
  k_dinv<<<(N + 255) / 256, 256, 0, stream>>>(deg, dinv, N);
  k_scan1<<<nb, SCAN_T, 0, stream>>>(deg, rowptr, bsum, N);
  k_scan2<<<1, SCAN_T, 0, stream>>>(bsum, nb);
  k_scan3<<<(N + 255) / 256, 256, 0, stream>>>(rowptr, bsum, N, E);
  k_fill<<<(E + 255) / 256, 256, 0, stream>>>(src, dst, dinv, rowptr, fillc, csr, E);

  // layer 1: tile 64 rows/block
  k_gemm<128, 64><<<(N + 63) / 64, 256, 0, stream>>>(x, W1, bufA, N);
  k_agg<64, true><<<(N + 3) / 4, 256, 0, stream>>>(bufA, bufB, rowptr, csr,
                                                   b1, g1, be1, m1, v1, N);
  // layer 2
  k_gemm<64, 64><<<(N + 63) / 64, 256, 0, stream>>>(bufB, W2, bufA, N);
  k_agg<64, true><<<(N + 3) / 4, 256, 0, stream>>>(bufA, bufB, rowptr, csr,
                                                   b2, g2, be2, m2, v2, N);
  // output layer: tile 100 rows/block
  k_gemm<64, 40><<<(N + 99) / 100, 256, 0, stream>>>(bufB, W3, bufA, N);
  k_agg<40, false><<<(N + 3) / 4, 256, 0, stream>>>(
      bufA, (float*)d_out, rowptr, csr, b3, nullptr, nullptr, nullptr, nullptr, N);
}